// Round 1
// baseline (364.072 us; speedup 1.0000x reference)
//
#include <hip/hip_runtime.h>
#include <stdint.h>

// ---------------------------------------------------------------------------
// GSDepthRankingLoss on MI355X.
// Reproduces JAX threefry2x32 PRNG (partitionable mode, the modern default)
// so the randomly-sampled indices match the reference bit-exactly.
// ---------------------------------------------------------------------------

#define JAX_PARTITIONABLE 1   // flip to 0 if harness JAX uses legacy threefry counters

#define IMG_W 1920
#define IMG_H 1080
#define N_SAMP 518400         // int(1920*1080*0.25)
#define RADIUS 3
#define PAD_VAL (-1000000.0f)

struct Keys { uint32_t k[5][2][2]; };  // [randint id][k1|k2][key word]

// Threefry-2x32, 20 rounds (Random123 / JAX-compatible).
static __host__ __device__ inline void tf2x32(uint32_t k0, uint32_t k1,
                                              uint32_t x0, uint32_t x1,
                                              uint32_t& o0, uint32_t& o1)
{
  const uint32_t ks2 = k0 ^ k1 ^ 0x1BD11BDAu;
  x0 += k0; x1 += k1;
#define TFR(r) { x0 += x1; x1 = (x1 << (r)) | (x1 >> (32 - (r))); x1 ^= x0; }
  TFR(13) TFR(15) TFR(26) TFR(6)
  x0 += k1;  x1 += ks2 + 1u;
  TFR(17) TFR(29) TFR(16) TFR(24)
  x0 += ks2; x1 += k0 + 2u;
  TFR(13) TFR(15) TFR(26) TFR(6)
  x0 += k0;  x1 += k1 + 3u;
  TFR(17) TFR(29) TFR(16) TFR(24)
  x0 += k1;  x1 += ks2 + 4u;
  TFR(13) TFR(15) TFR(26) TFR(6)
  x0 += ks2; x1 += k0 + 5u;
#undef TFR
  o0 = x0; o1 = x1;
}

// random_bits(key, 32, shape)[f]; S = total flat size (used only in legacy mode)
__device__ inline uint32_t jrbits(const uint32_t kk[2], uint32_t f, uint32_t S)
{
#if JAX_PARTITIONABLE
  (void)S;
  uint32_t a, b;
  tf2x32(kk[0], kk[1], 0u, f, a, b);   // counts are 64-bit iota: (hi=0, lo=f)
  return a ^ b;                        // 32-bit fold
#else
  const uint32_t half = S >> 1;
  uint32_t a, b;
  if (f < half) { tf2x32(kk[0], kk[1], f, half + f, a, b); return a; }
  tf2x32(kk[0], kk[1], f - half, f, a, b); return b;
#endif
}

// jax.random.randint offset (minval added by caller). span < 2^16 here.
__device__ inline uint32_t jrandint(const Keys& K, int r, uint32_t f,
                                    uint32_t span, uint32_t S)
{
  const uint32_t hi = jrbits(K.k[r][0], f, S);
  const uint32_t lo = jrbits(K.k[r][1], f, S);
  uint32_t m = 65536u % span;
  m = (m * m) % span;
  return ((hi % span) * m + (lo % span)) % span;
}

static void compute_keys(Keys& K)
{
  uint32_t ks[5][2];
#if JAX_PARTITIONABLE
  for (uint32_t t = 0; t < 5; t++) {
    uint32_t a, b; tf2x32(0u, 42u, 0u, t, a, b);   // fold-like split of key(42)
    ks[t][0] = a; ks[t][1] = b;
  }
  for (int r = 0; r < 5; r++) {                    // randint's internal _split
    uint32_t a, b;
    tf2x32(ks[r][0], ks[r][1], 0u, 0u, a, b); K.k[r][0][0] = a; K.k[r][0][1] = b;
    tf2x32(ks[r][0], ks[r][1], 0u, 1u, a, b); K.k[r][1][0] = a; K.k[r][1][1] = b;
  }
#else
  uint32_t o[10];
  for (uint32_t f = 0; f < 5; f++) {
    uint32_t a, b; tf2x32(0u, 42u, f, 5u + f, a, b);
    o[f] = a; o[5 + f] = b;
  }
  for (int t = 0; t < 5; t++) { ks[t][0] = o[2 * t]; ks[t][1] = o[2 * t + 1]; }
  for (int r = 0; r < 5; r++) {
    uint32_t a0, b0, a1, b1;
    tf2x32(ks[r][0], ks[r][1], 0u, 2u, a0, b0);
    tf2x32(ks[r][0], ks[r][1], 1u, 3u, a1, b1);
    K.k[r][0][0] = a0; K.k[r][0][1] = a1;
    K.k[r][1][0] = b0; K.k[r][1][1] = b1;
  }
#endif
}

__global__ __launch_bounds__(256) void gs_main(
    const float* __restrict__ tgt,   // target depths (H*W)
    const float* __restrict__ rnd,   // render depths (H*W)
    const int*   __restrict__ vmask, // valid mask   (H*W)
    float* __restrict__ acc,         // ws: [rank_sum, cont_sum, count]
    Keys K)
{
  const int i = blockIdx.x * blockDim.x + threadIdx.x;
  float rank_c = 0.f, cont_c = 0.f, cnt_c = 0.f;

  if (i < N_SAMP) {
    const uint32_t ui = (uint32_t)i;
    const uint32_t syb = jrandint(K, 0, ui, 840u,  N_SAMP);   // H - 240
    const uint32_t sxb = jrandint(K, 1, ui, 1680u, N_SAMP);   // W - 240

    int sy[2], sx[2], sidx[2];
    float sd[2];
    bool sm = true;
#pragma unroll
    for (int j = 0; j < 2; j++) {
      sy[j] = (int)(syb + jrandint(K, 2, 2u * ui + (uint32_t)j, 240u, 2u * N_SAMP));
      sx[j] = (int)(sxb + jrandint(K, 3, 2u * ui + (uint32_t)j, 240u, 2u * N_SAMP));
      sidx[j] = sy[j] * IMG_W + sx[j];
      sd[j] = tgt[sidx[j]];
      sm = sm && (vmask[sidx[j]] != 0);
    }

    if (sm) {  // full_mask == 0 contributes nothing -> skip heavy work
      int nidx[2];
      bool nm = true;
#pragma unroll
      for (int j = 0; j < 2; j++) {
        // 15 smallest of 49 keys; key = (|diff|_bits << 6) | pos  (unique,
        // stable-tie == argsort stable). Pads rank >=16 (>=16 cells in-bounds).
        unsigned long long arr[15];
#pragma unroll
        for (int t = 0; t < 15; t++) arr[t] = ~0ull;

        const float sdj = sd[j];
        int q = 0;
        for (int ry = 0; ry < 7; ry++) {
          const int yy = sy[j] - RADIUS + ry;
          const bool rok = (yy >= 0) && (yy < IMG_H);
          const float* rowp = tgt + yy * IMG_W;
          for (int rx = 0; rx < 7; rx++, q++) {
            const int xx = sx[j] - RADIUS + rx;
            float v = PAD_VAL;
            if (rok && xx >= 0 && xx < IMG_W) v = rowp[xx];
            const float df = fabsf(v - sdj);  // non-negative: bits are monotone
            unsigned long long key =
                (((unsigned long long)__float_as_uint(df)) << 6) | (unsigned)q;
#pragma unroll
            for (int t = 0; t < 15; t++) {   // bubble-insert network
              const bool c = key < arr[t];
              const unsigned long long lo = c ? key : arr[t];
              key = c ? arr[t] : key;
              arr[t] = lo;
            }
          }
        }

        const uint32_t nbr =
            1u + jrandint(K, 4, 2u * ui + (uint32_t)j, 14u, 2u * N_SAMP); // [1,15)
        uint32_t rel = 0;
#pragma unroll
        for (int t = 1; t < 15; t++)
          if ((uint32_t)t == nbr) rel = (uint32_t)(arr[t] & 63ull);

        const int ny = sy[j] - RADIUS + (int)(rel / 7u);
        const int nx = sx[j] - RADIUS + (int)(rel % 7u);
        nidx[j] = ny * IMG_W + nx;
        nm = nm && (vmask[nidx[j]] != 0);
      }

      if (nm) {
        const float r0 = rnd[sidx[0]], r1 = rnd[sidx[1]];
        const float q0 = rnd[nidx[0]], q1 = rnd[nidx[1]];
        const bool keep = sd[0] >= sd[1];          // stable argsort(-depth)
        const float ra = keep ? r0 : r1;
        const float rb = keep ? r1 : r0;
        rank_c = fmaxf(ra - rb + 1e-4f, 0.f);
        // cont is permutation-invariant across the pair
        cont_c = fmaxf(fabsf(r0 - q0) - 1e-4f, 0.f)
               + fmaxf(fabsf(r1 - q1) - 1e-4f, 0.f);
        cnt_c = 1.f;
      }
    }
  }

  // wave(64) shuffle reduction, one atomic triple per wave
#pragma unroll
  for (int off = 32; off > 0; off >>= 1) {
    rank_c += __shfl_down(rank_c, off);
    cont_c += __shfl_down(cont_c, off);
    cnt_c  += __shfl_down(cnt_c, off);
  }
  if ((threadIdx.x & 63) == 0) {
    atomicAdd(acc + 0, rank_c);
    atomicAdd(acc + 1, cont_c);
    atomicAdd(acc + 2, cnt_c);
  }
}

__global__ void gs_finalize(const float* __restrict__ acc, float* __restrict__ out)
{
  const float denom = fmaxf(acc[2], 1.0f);
  out[0] = 0.2f * (acc[0] / denom);                 // WEIGHT * rank_mean
  out[1] = 0.2f * 0.1f * (acc[1] / (denom * 2.0f)); // WEIGHT*CONT_W * cont_mean
}

extern "C" void kernel_launch(void* const* d_in, const int* in_sizes, int n_in,
                              void* d_out, int out_size, void* d_ws, size_t ws_size,
                              hipStream_t stream)
{
  (void)in_sizes; (void)n_in; (void)out_size; (void)ws_size;
  const float* tgt   = (const float*)d_in[0];
  const float* rnd   = (const float*)d_in[1];
  const int*   vmask = (const int*)d_in[2];
  float* out = (float*)d_out;
  float* acc = (float*)d_ws;

  Keys K;
  compute_keys(K);

  hipMemsetAsync(acc, 0, 3 * sizeof(float), stream);
  const int threads = 256;
  const int blocks = (N_SAMP + threads - 1) / threads;
  gs_main<<<blocks, threads, 0, stream>>>(tgt, rnd, vmask, acc, K);
  gs_finalize<<<1, 1, 0, stream>>>(acc, out);
}